// Round 7
// baseline (287.934 us; speedup 1.0000x reference)
//
#include <hip/hip_runtime.h>
#include <stdint.h>
#include <math.h>

// ---------------------------------------------------------------------------
// HardNegativeMiner round 7: persistent-block pipelined k_main.
//  - 512 persistent blocks, each owns a fixed 128-col c-block (L2-hot B) and
//    iterates 6-7 j-tiles.
//  - K-chunk double-buffer (64 KB LDS): chunk kc+1's global_load_lds issued
//    before chunk kc's MFMAs, so the pre-barrier vmcnt(0) drain is hidden
//    behind the MFMA phase; next tile's chunk 0 is prefetched before the
//    epilogue, hiding its drain behind ~4.5 us of threefry VALU.
// PRNG chain (partitionable threefry) verified bit-exact in rounds 1-6.
// ---------------------------------------------------------------------------
#define BN 16384   // batch
#define DK 256     // dim
#define NH 3276    // int(16384*0.2)
#define NTILE 3328 // 26 j-strips * 128 c-blocks
#define NBLK 512   // persistent blocks (2/CU)

typedef __attribute__((ext_vector_type(8))) short short8;
typedef __attribute__((ext_vector_type(4))) short short4v;
typedef __attribute__((ext_vector_type(4))) float f32x4;

__host__ __device__ __forceinline__ void tf2x32(uint32_t k0, uint32_t k1,
                                                uint32_t c0, uint32_t c1,
                                                uint32_t& o0, uint32_t& o1) {
  uint32_t ks2 = 0x1BD11BDAu ^ k0 ^ k1;
  uint32_t x0 = c0 + k0, x1 = c1 + k1;
#define RR(d) { x0 += x1; x1 = (x1 << d) | (x1 >> (32 - d)); x1 ^= x0; }
  RR(13) RR(15) RR(26) RR(6)   x0 += k1;  x1 += ks2 + 1u;
  RR(17) RR(29) RR(16) RR(24)  x0 += ks2; x1 += k0  + 2u;
  RR(13) RR(15) RR(26) RR(6)   x0 += k0;  x1 += k1  + 3u;
  RR(17) RR(29) RR(16) RR(24)  x0 += k1;  x1 += ks2 + 4u;
  RR(13) RR(15) RR(26) RR(6)   x0 += ks2; x1 += k0  + 5u;
#undef RR
  o0 = x0; o1 = x1;
}

__device__ __forceinline__ uint32_t rand32_at(uint32_t k0, uint32_t k1, uint32_t p) {
  uint32_t x0, x1; tf2x32(k0, k1, 0u, p, x0, x1);
  return x0 ^ x1;
}

__device__ __forceinline__ float unif01_from_bits(uint32_t bits) {
  return __uint_as_float((bits >> 9) | 0x3f800000u) - 1.0f;
}

// gumbel at flat counter p: -log(-log(max(u, tiny))), fast v_log_f32 path
__device__ __forceinline__ float gumbel_at(uint32_t k0, uint32_t k1, uint32_t p) {
  uint32_t bits = rand32_at(k0, k1, p);
  float f = unif01_from_bits(bits);
  float u = fmaxf(f, 1.17549435e-38f);             // minval = finfo(f32).tiny
  float t = __log2f(u) * (-0.69314718055994531f);  // -ln(u) > 0
  return __log2f(t) * (-0.69314718055994531f);     // -ln(t)
}

// monotonic float->u32; pack (value, ~col): max => larger val, tie => smaller col
__device__ __forceinline__ unsigned long long packvc(float v, uint32_t c) {
  uint32_t u = __float_as_uint(v);
  u ^= ((int32_t)u < 0) ? 0xFFFFFFFFu : 0x80000000u;
  return ((unsigned long long)u << 32) | (unsigned long long)(~c);
}

// 16-byte global -> LDS async DMA. LDS dest is wave-uniform base + lane*16.
__device__ __forceinline__ void glds16(const unsigned short* g, short* l) {
  __builtin_amdgcn_global_load_lds(
      (const __attribute__((address_space(1))) void*)g,
      (__attribute__((address_space(3))) void*)l, 16, 0, 0);
}

// ---------------------------------------------------------------------------
// Fused: row inv-norm + split-bf16 copy of z*inv (GEMM acc == sim directly)
// + src_idx/best setup.
__global__ __launch_bounds__(256) void k_prep(const float* __restrict__ z,
                                              unsigned short* __restrict__ zh,
                                              unsigned short* __restrict__ zl,
                                              int* __restrict__ src_idx,
                                              unsigned long long* __restrict__ best,
                                              uint32_t k20, uint32_t k21) {
  int b = blockIdx.x, t = threadIdx.x;
  if (b < BN / 4) {
    int row = b * 4 + (t >> 6), lane = t & 63;
    float4 v = *(const float4*)&z[row * DK + lane * 4];
    float ss = v.x * v.x + v.y * v.y + v.z * v.z + v.w * v.w;
#pragma unroll
    for (int off = 32; off; off >>= 1) ss += __shfl_xor(ss, off, 64);
    float inv = 1.0f / fmaxf(sqrtf(ss), 1e-12f);
    float f[4] = {v.x * inv, v.y * inv, v.z * inv, v.w * inv};
    short4v h, l;
#pragma unroll
    for (int i = 0; i < 4; ++i) {
      uint32_t u = __float_as_uint(f[i]);
      h[i] = (short)(u >> 16);
      float r = f[i] - __uint_as_float(u & 0xFFFF0000u);
      l[i] = (short)(__float_as_uint(r) >> 16);
    }
    *(short4v*)&zh[row * DK + lane * 4] = h;
    *(short4v*)&zl[row * DK + lane * 4] = l;
  } else {
    int i = (b - BN / 4) * 256 + t;
    if (i < NH) {
      uint32_t bits = rand32_at(k20, k21, (uint32_t)i);
      src_idx[i] = (int)(bits & (uint32_t)(BN - 1));  // randint span 2^14
      best[i] = 0ull;                                 // identity for packvc keys
    }
  }
}

// ---------------------------------------------------------------------------
// Persistent pipelined k_main. Tile flat id = blockIdx.x + NBLK*it.
// Mapping: xcd = flat&7, slot = flat>>3, c-block = slot&15, j-strip = slot>>4.
// NBLK = 512 = 8*64 -> xcd and c-block are block-constant; j = j0 + 4*it.
__global__ __launch_bounds__(256, 2) void k_main(const unsigned short* __restrict__ zh,
                                                 const unsigned short* __restrict__ zl,
                                                 const int* __restrict__ src_idx,
                                                 unsigned long long* __restrict__ best,
                                                 uint32_t kt0, uint32_t kt1) {
  // 2 parity buffers per tile-matrix: 4 arrays x 2 x 4096 shorts = 64 KB
  __shared__ __align__(16) short As_hi[2 * 4096];
  __shared__ __align__(16) short As_lo[2 * 4096];
  __shared__ __align__(16) short Bs_hi[2 * 4096];
  __shared__ __align__(16) short Bs_lo[2 * 4096];

  const int b = blockIdx.x;
  const int xcd = b & 7;
  const int cslot = (b >> 3) & 15;
  const int c_base = (xcd * 16 + cslot) * 128;
  const int j0 = b >> 7;                     // j for it=0; j = j0 + 4*it
  const int ntiles = (b < 256) ? 7 : 6;      // flat < 3328

  const int t = threadIdx.x;
  const int lane = t & 63, w = t >> 6;

  // staging geometry (tile-invariant): wave w owns rows [32w,32w+32)
  const int r0 = w * 32 + (lane >> 2);
  const int r1 = r0 + 16;
  const int u0 = (lane & 3) ^ ((r0 >> 1) & 3);   // swizzle-inverted data unit
  const int u1 = (lane & 3) ^ ((r1 >> 1) & 3);
  const uint32_t offB0 = (uint32_t)((c_base + r0) * DK + u0 * 8);  // block-const
  const uint32_t offB1 = (uint32_t)((c_base + r1) * DK + u1 * 8);

  // fragment roles (kc-invariant LDS offsets within a parity buffer)
  const int cl = lane & 15, q = lane >> 4;
  const int mb = (w >> 1) * 64 + cl;
  const int nb = (w & 1) * 64 + cl;
  int foffA[4], foffB[4];
#pragma unroll
  for (int i = 0; i < 4; ++i) {
    int ra = mb + i * 16, rb = nb + i * 16;
    foffA[i] = ra * 32 + (q ^ ((ra >> 1) & 3)) * 8;
    foffB[i] = rb * 32 + (q ^ ((rb >> 1) & 3)) * 8;
  }
  const int ldsw = w * 1024;   // this wave's 16-row slice inside a parity buf

  // A-row offsets for current tile (loaded one tile ahead)
  uint32_t offA0 = (uint32_t)(src_idx[min(j0 * 128 + r0, NH - 1)] * DK + u0 * 8);
  uint32_t offA1 = (uint32_t)(src_idx[min(j0 * 128 + r1, NH - 1)] * DK + u1 * 8);

  // prime the pipe: tile 0 chunk 0 -> parity 0
  glds16(zh + offA0, &As_hi[ldsw]);
  glds16(zh + offA1, &As_hi[ldsw + 512]);
  glds16(zl + offA0, &As_lo[ldsw]);
  glds16(zl + offA1, &As_lo[ldsw + 512]);
  glds16(zh + offB0, &Bs_hi[ldsw]);
  glds16(zh + offB1, &Bs_hi[ldsw + 512]);
  glds16(zl + offB0, &Bs_lo[ldsw]);
  glds16(zl + offB1, &Bs_lo[ldsw + 512]);

  for (int it = 0; it < ntiles; ++it) {
    const int j_base = (j0 + 4 * it) * 128;
    // next tile's A rows (for the kc==7 prefetch)
    uint32_t nA0 = 0, nA1 = 0;
    const bool have_next = (it + 1 < ntiles);
    if (have_next) {
      int njb = (j0 + 4 * (it + 1)) * 128;
      nA0 = (uint32_t)(src_idx[min(njb + r0, NH - 1)] * DK + u0 * 8);
      nA1 = (uint32_t)(src_idx[min(njb + r1, NH - 1)] * DK + u1 * 8);
    }

    f32x4 acc[4][4];
#pragma unroll
    for (int mt = 0; mt < 4; ++mt)
#pragma unroll
      for (int nt = 0; nt < 4; ++nt) acc[mt][nt] = (f32x4){0.f, 0.f, 0.f, 0.f};

#pragma unroll
    for (int kc = 0; kc < 8; ++kc) {
      const int pc = (kc & 1) * 4096;        // parity being computed
      const int pn = ((kc + 1) & 1) * 4096;  // parity being filled
      __syncthreads();  // drains DMA for parity pc (issued last iter / prologue)
      if (kc < 7) {
        const int ko = (kc + 1) * 32;
        glds16(zh + offA0 + ko, &As_hi[pn + ldsw]);
        glds16(zh + offA1 + ko, &As_hi[pn + ldsw + 512]);
        glds16(zl + offA0 + ko, &As_lo[pn + ldsw]);
        glds16(zl + offA1 + ko, &As_lo[pn + ldsw + 512]);
        glds16(zh + offB0 + ko, &Bs_hi[pn + ldsw]);
        glds16(zh + offB1 + ko, &Bs_hi[pn + ldsw + 512]);
        glds16(zl + offB0 + ko, &Bs_lo[pn + ldsw]);
        glds16(zl + offB1 + ko, &Bs_lo[pn + ldsw + 512]);
      } else if (have_next) {
        // prefetch next tile chunk 0 -> parity 0; drain hidden by epilogue
        glds16(zh + nA0, &As_hi[ldsw]);
        glds16(zh + nA1, &As_hi[ldsw + 512]);
        glds16(zl + nA0, &As_lo[ldsw]);
        glds16(zl + nA1, &As_lo[ldsw + 512]);
        glds16(zh + offB0, &Bs_hi[ldsw]);
        glds16(zh + offB1, &Bs_hi[ldsw + 512]);
        glds16(zl + offB0, &Bs_lo[ldsw]);
        glds16(zl + offB1, &Bs_lo[ldsw + 512]);
      }

      short8 bh[4], bl[4];
#pragma unroll
      for (int nt = 0; nt < 4; ++nt) {
        bh[nt] = *(const short8*)&Bs_hi[pc + foffB[nt]];
        bl[nt] = *(const short8*)&Bs_lo[pc + foffB[nt]];
      }
#pragma unroll
      for (int mt = 0; mt < 4; ++mt) {
        short8 ah = *(const short8*)&As_hi[pc + foffA[mt]];
        short8 al = *(const short8*)&As_lo[pc + foffA[mt]];
#pragma unroll
        for (int nt = 0; nt < 4; ++nt) {
          acc[mt][nt] = __builtin_amdgcn_mfma_f32_16x16x32_bf16(ah, bh[nt], acc[mt][nt], 0, 0, 0);
          acc[mt][nt] = __builtin_amdgcn_mfma_f32_16x16x32_bf16(ah, bl[nt], acc[mt][nt], 0, 0, 0);
          acc[mt][nt] = __builtin_amdgcn_mfma_f32_16x16x32_bf16(al, bh[nt], acc[mt][nt], 0, 0, 0);
        }
      }
    }
    offA0 = nA0; offA1 = nA1;

    // ---- epilogue: acc==sim; tot = fmaf(sim,10,gumbel); argmax 64 cols ----
    const int q4 = (lane >> 4) * 4;
    const int coff = c_base + (w & 1) * 64;
    const int roff = j_base + (w >> 1) * 64;
    const uint32_t ccl = (uint32_t)(coff + cl);
#pragma unroll
    for (int mt = 0; mt < 4; ++mt)
#pragma unroll
      for (int r = 0; r < 4; ++r) {
        int gj = roff + mt * 16 + q4 + r;
        int s = src_idx[min(gj, NH - 1)];
        uint32_t pbase = (uint32_t)gj * (uint32_t)BN + ccl;
        float bv = -INFINITY; uint32_t bc = 0;
#pragma unroll
        for (int nt = 0; nt < 4; ++nt) {
          uint32_t c = ccl + (uint32_t)(nt * 16);
          float gv = gumbel_at(kt0, kt1, pbase + (uint32_t)(nt * 16));
          float tot = fmaf(acc[mt][nt][r], 10.0f, gv);   // logits = sim / 0.1
          tot = ((int)c == s) ? -INFINITY : tot;         // diagonal mask
          if (tot > bv) { bv = tot; bc = c; }
        }
        unsigned long long key = packvc(bv, bc);
#pragma unroll
        for (int off = 1; off <= 8; off <<= 1) {
          unsigned long long o = __shfl_xor(key, off, 64);
          if (o > key) key = o;
        }
        if (cl == 0 && gj < NH) atomicMax(&best[gj], key);
      }
  }
}

__global__ __launch_bounds__(64) void k_out(const float* __restrict__ z,
                                            const int* __restrict__ src_idx,
                                            const unsigned long long* __restrict__ best,
                                            float* __restrict__ out,
                                            uint32_t ka0, uint32_t ka1) {
  int j = blockIdx.x;
  int lane = threadIdx.x;
  int s = src_idx[j];
  int tgt = (int)(~((uint32_t)(best[j] & 0xFFFFFFFFull)));
  uint32_t bits = rand32_at(ka0, ka1, (uint32_t)j);
  float alpha = unif01_from_bits(bits) * 0.5f;   // uniform * MIX_ALPHA
  float om = 1.0f - alpha;
  float4 a = *(const float4*)&z[s * DK + lane * 4];
  float4 b = *(const float4*)&z[tgt * DK + lane * 4];
  float4 o;
  o.x = alpha * a.x + om * b.x;
  o.y = alpha * a.y + om * b.y;
  o.z = alpha * a.z + om * b.z;
  o.w = alpha * a.w + om * b.w;
  *(float4*)&out[j * DK + lane * 4] = o;
}

// ---------------------------------------------------------------------------
extern "C" void kernel_launch(void* const* d_in, const int* in_sizes, int n_in,
                              void* d_out, int out_size, void* d_ws, size_t ws_size,
                              hipStream_t stream) {
  const float* z = (const float*)d_in[0];
  float* out = (float*)d_out;
  char* ws = (char*)d_ws;
  // ws layout (~16.8 MB):
  int*                src_idx = (int*)(ws);                        // 16 KB
  unsigned long long* best    = (unsigned long long*)(ws + 16384); // 32 KB
  unsigned short*     zh      = (unsigned short*)(ws + 65536);     // 8.39 MB
  unsigned short*     zl      = (unsigned short*)(ws + 65536 + 8388608);

  // host-side threefry key derivation (partitionable scheme, verified round 1)
  uint32_t r0 = 0u, r1 = 42u;
  uint32_t ks0, ks1, kt0, kt1, ka0, ka1, k20, k21;
  tf2x32(r0, r1, 0u, 0u, ks0, ks1);   // k_src   = split(root,3)[0]
  tf2x32(r0, r1, 0u, 1u, kt0, kt1);   // k_tgt   = split(root,3)[1]
  tf2x32(r0, r1, 0u, 2u, ka0, ka1);   // k_alpha = split(root,3)[2]
  tf2x32(ks0, ks1, 0u, 1u, k20, k21); // split(k_src,2)[1] (randint lower bits)

  k_prep<<<dim3(BN / 4 + (NH + 255) / 256), dim3(256), 0, stream>>>(
      z, zh, zl, src_idx, best, k20, k21);
  k_main<<<dim3(NBLK), dim3(256), 0, stream>>>(zh, zl, src_idx, best, kt0, kt1);
  k_out <<<dim3(NH), dim3(64), 0, stream>>>(z, src_idx, best, out, ka0, ka1);
}